// Round 2
// baseline (79.123 us; speedup 1.0000x reference)
//
#include <hip/hip_runtime.h>

#define PAD 15
#define LOG2E 1.4426950408889634f
#define LN2   0.6931471805599453f

// DPP ctrl codes (within-16-lane-row ops, full-rate VALU)
#define DPP_X1  0xB1   // quad_perm [1,0,3,2]  -> lane ^ 1
#define DPP_X2  0x4E   // quad_perm [2,3,0,1]  -> lane ^ 2
#define DPP_X7  0x141  // row_half_mirror      -> lane ^ 7
#define DPP_X15 0x140  // row_mirror           -> lane ^ 15

template<int CTRL>
__device__ __forceinline__ float dppf(float x) {
  int r = __builtin_amdgcn_update_dpp(0, __builtin_bit_cast(int, x), CTRL, 0xF, 0xF, true);
  return __builtin_bit_cast(float, r);
}

// Butterfly all-gather: after this, g[r] = share(lane j ^ xm[r]) where
// xm = {0,1,2,3,7,6,5,4,15,14,13,12,8,9,10,11}
__device__ __forceinline__ void gather16(float share, float* g) {
  g[0] = share;
  g[1] = dppf<DPP_X1>(g[0]);
  g[2] = dppf<DPP_X2>(g[0]);  g[3] = dppf<DPP_X2>(g[1]);
  g[4] = dppf<DPP_X7>(g[0]);  g[5] = dppf<DPP_X7>(g[1]);
  g[6] = dppf<DPP_X7>(g[2]);  g[7] = dppf<DPP_X7>(g[3]);
  g[8]  = dppf<DPP_X15>(g[0]); g[9]  = dppf<DPP_X15>(g[1]);
  g[10] = dppf<DPP_X15>(g[2]); g[11] = dppf<DPP_X15>(g[3]);
  g[12] = dppf<DPP_X15>(g[4]); g[13] = dppf<DPP_X15>(g[5]);
  g[14] = dppf<DPP_X15>(g[6]); g[15] = dppf<DPP_X15>(g[7]);
}

__device__ __forceinline__ float max16(const float* g) {
  float a = fmaxf(g[0], g[1]),  b = fmaxf(g[2], g[3]);
  float c = fmaxf(g[4], g[5]),  d = fmaxf(g[6], g[7]);
  float e = fmaxf(g[8], g[9]),  f = fmaxf(g[10], g[11]);
  float h = fmaxf(g[12], g[13]), i = fmaxf(g[14], g[15]);
  return fmaxf(fmaxf(fmaxf(a, b), fmaxf(c, d)), fmaxf(fmaxf(e, f), fmaxf(h, i)));
}

__device__ __forceinline__ float dot16(const float* g, const float* W) {
  float d0 = g[0] * W[0], d1 = g[1] * W[1], d2 = g[2] * W[2], d3 = g[3] * W[3];
  d0 = fmaf(g[4],  W[4],  d0); d1 = fmaf(g[5],  W[5],  d1);
  d2 = fmaf(g[6],  W[6],  d2); d3 = fmaf(g[7],  W[7],  d3);
  d0 = fmaf(g[8],  W[8],  d0); d1 = fmaf(g[9],  W[9],  d1);
  d2 = fmaf(g[10], W[10], d2); d3 = fmaf(g[11], W[11], d3);
  d0 = fmaf(g[12], W[12], d0); d1 = fmaf(g[13], W[13], d1);
  d2 = fmaf(g[14], W[14], d2); d3 = fmaf(g[15], W[15], d3);
  return (d0 + d1) + (d2 + d3);
}

// One unified fwd/bwd CRF step in the exp2 domain.
// fwd: E'[j] = p_j * sum_i E[i] * W[i][j]      (share E, scale after dot)
// bwd: B'[i] = sum_k W[i][k] * (B[k] * p_k)    (scale before share)
template<bool RN>
__device__ __forceinline__ void crf_step(float emit, int yv, bool isBwd,
                                         const float* Wg, float& own, float& M) {
  const float p = exp2f(emit * LOG2E);
  const float share = own * (isBwd ? p : 1.0f);
  float g[16];
  gather16(share, g);
  const float tot = dot16(g, Wg);
  const float cand = tot * (isBwd ? 1.0f : p);
  own = (yv != PAD) ? cand : own;
  if (RN) {  // renormalize every 8 steps; drift bounded ~2^110 < f32 range
    const float m = max16(g);
    const float rs = __builtin_amdgcn_rcpf(m);
    own *= rs;
    M += log2f(m);
  }
}

__global__ __launch_bounds__(256, 2)
void crf_kernel(const float* __restrict__ logits, const int* __restrict__ yg,
                const float* __restrict__ trans, float* __restrict__ out) {
  __shared__ float Tl[240];
  __shared__ float comb[8][2][16];
  __shared__ float path8[8];
  __shared__ float blks[8];

  const int tid = threadIdx.x;
  if (tid < 225) Tl[tid] = trans[tid];
  __syncthreads();

  const char* lb = (const char*)logits;
  const char* yb = (const char*)yg;

  // ---------- phase 1: path score (parallel over t; 32 threads / sequence) ----------
  {
    const int q = tid >> 5;
    const int l32 = tid & 31;
    const int ps = blockIdx.x * 8 + q;
    const int ybase = ps * 2048;     // 512 * 4 B
    const int ebase = ps * 30720;    // 512 * 15 * 4 B
    float acc = 0.0f;
    #pragma unroll
    for (int m = 0; m < 16; ++m) {
      const int t = l32 + 32 * m;
      const int yc = *(const int*)(yb + ybase + t * 4);
      if (yc != PAD) {
        acc += *(const float*)(lb + ebase + t * 60 + yc * 4);
        if (t > 0) {
          const int yp = *(const int*)(yb + ybase + t * 4 - 4);
          if (yp != PAD) acc += Tl[yp * 15 + yc];
        }
      }
    }
    #pragma unroll
    for (int k = 1; k < 32; k <<= 1) acc += __shfl_xor(acc, k, 32);
    if (l32 == 0) path8[q] = acc;
  }

  // ---------- chain setup: 16 lanes per chain, 4 chains/wave ----------
  const int lane = tid & 63;
  const int wave = tid >> 6;
  const int row  = lane >> 4;
  const int j    = lane & 15;
  const int jj   = (j < 15) ? j : 14;      // lane 15 is inert (tag pad)
  const int chain = wave * 4 + row;        // 0..15
  const int sloc  = chain >> 1;            // 0..7 local sequence
  const bool isBwd = (chain & 1) != 0;
  const int seq = blockIdx.x * 8 + sloc;

  // W in butterfly-gather order; zero where either tag == 15
  constexpr int xm[16] = {0, 1, 2, 3, 7, 6, 5, 4, 15, 14, 13, 12, 8, 9, 10, 11};
  float Wg[16];
  #pragma unroll
  for (int r = 0; r < 16; ++r) {
    const int src = j ^ xm[r];
    const bool valid = (j < 15) && (src < 15);
    const int ti = valid ? (isBwd ? j * 15 + src : src * 15 + j) : 0;
    Wg[r] = valid ? exp2f(Tl[ti] * LOG2E) : 0.0f;
  }

  // 8-deep prefetch rings for emit (own tag) and labels (mask)
  int eoff = seq * 30720 + (isBwd ? 511 * 60 : 0) + jj * 4;
  int yoff = seq * 2048 + (isBwd ? 511 * 4 : 0);
  const int de = isBwd ? -60 : 60;
  const int dy = isBwd ? -4 : 4;

  float buf[8]; int ybuf[8];
  #pragma unroll
  for (int i = 0; i < 8; ++i) {
    buf[i]  = *(const float*)(lb + (eoff + i * de));
    ybuf[i] = *(const int*)(yb + (yoff + i * dy));
  }
  int peoff = eoff + 8 * de;
  int pyoff = yoff + 8 * dy;

  // state init (branch-free; bwd lanes discard the fwd-init computation)
  const float a0 = buf[0];
  const float A = (j < 15) ? a0 * LOG2E : -1.0e30f;
  float gi[16];
  gather16(A, gi);
  const float Mf = max16(gi);
  float own = isBwd ? ((j < 15) ? 1.0f : 0.0f) : exp2f(A - Mf);
  float M   = isBwd ? 0.0f : Mf;
  if (!isBwd) ybuf[0] = PAD;   // fwd step s=0 is a masked no-op (t=0 is the init)

  // ---------- main scan: 256 unified steps (fwd t=1..255, bwd t=511..256) ----------
  for (int sb = 0; sb < 32; ++sb) {
    #pragma unroll
    for (int kk = 0; kk < 8; ++kk) {
      const float emit = buf[kk];
      const int yv = ybuf[kk];
      buf[kk]  = *(const float*)(lb + peoff);     // prefetch 8 steps ahead
      ybuf[kk] = *(const int*)(yb + pyoff);
      peoff += de; pyoff += dy;
      if (kk == 7) crf_step<true>(emit, yv, isBwd, Wg, own, M);
      else         crf_step<false>(emit, yv, isBwd, Wg, own, M);
    }
  }

  // ---------- combine: logZ = lse_i(alpha_255[i] + beta_255[i]) ----------
  const float logv = (j < 15 && own > 0.0f) ? (M + log2f(own)) : -1.0e30f;
  comb[sloc][isBwd ? 1 : 0][j] = logv;
  __syncthreads();

  if (tid < 8) {
    float sv[15];
    float mx = -3.0e38f;
    #pragma unroll
    for (int i = 0; i < 15; ++i) {
      sv[i] = comb[tid][0][i] + comb[tid][1][i];
      mx = fmaxf(mx, sv[i]);
    }
    float vs = 0.0f;
    #pragma unroll
    for (int i = 0; i < 15; ++i) vs += exp2f(sv[i] - mx);
    const float logZ = (mx + log2f(vs)) * LN2;
    float nll = logZ - path8[tid];
    nll = fminf(fmaxf(nll, 0.0f), 1000000.0f);
    blks[tid] = nll;
  }
  __syncthreads();
  if (tid == 0) {
    float tot = (blks[0] + blks[1]) + (blks[2] + blks[3]) +
                (blks[4] + blks[5]) + (blks[6] + blks[7]);
    atomicAdd(out, tot * (1.0f / 4096.0f));
  }
}

extern "C" void kernel_launch(void* const* d_in, const int* in_sizes, int n_in,
                              void* d_out, int out_size, void* d_ws, size_t ws_size,
                              hipStream_t stream) {
  const float* logits = (const float*)d_in[0];   // (4096, 512, 15) f32
  const int*   y      = (const int*)d_in[1];     // (4096, 512) i32
  const float* trans  = (const float*)d_in[2];   // (15, 15) f32
  float* out = (float*)d_out;

  hipMemsetAsync(out, 0, sizeof(float), stream);

  const int B = in_sizes[1] / 512;               // 4096
  crf_kernel<<<dim3(B / 8), dim3(256), 0, stream>>>(logits, y, trans, out);
}

// Round 4
// 68.438 us; speedup vs baseline: 1.1561x; 1.1561x over previous
//
#include <hip/hip_runtime.h>

#define L2E  1.4426950408889634f
#define LN2f 0.6931471805599453f

template<int CTRL>
__device__ __forceinline__ float dppf(float x) {
  int r = __builtin_amdgcn_update_dpp(0, __builtin_bit_cast(int, x), CTRL, 0xF, 0xF, true);
  return __builtin_bit_cast(float, r);
}
template<int CTRL>
__device__ __forceinline__ int dppi(int x) {
  return __builtin_amdgcn_update_dpp(0, x, CTRL, 0xF, 0xF, true);
}

// max over the 16-lane group via DPP butterfly; xor set {1,2,7,15} spans 0..15
// (same ctrl set verified in round-2 kernel, absmax 0)
__device__ __forceinline__ float bflymax16(float x) {
  x = fmaxf(x, dppf<0xB1>(x));    // quad_perm -> lane^1
  x = fmaxf(x, dppf<0x4E>(x));    // quad_perm -> lane^2
  x = fmaxf(x, dppf<0x141>(x));   // row_half_mirror -> lane^7
  x = fmaxf(x, dppf<0x140>(x));   // row_mirror -> lane^15
  return x;
}

// Fused rotate-and-dot: tot_j = sum_r rot_r(shv)_j * Wror[r]_j.
// Wror was built with the TRUE source-lane of each rotation (dppi on lane id),
// so the rotation direction convention cancels out.
#define DOT(shv, tot) {                                   \
    float t0_ = (shv) * Wror[0], t1_ = 0.f, t2_ = 0.f, t3_ = 0.f; \
    t1_ = fmaf(dppf<0x121>(shv), Wror[1],  t1_);          \
    t2_ = fmaf(dppf<0x122>(shv), Wror[2],  t2_);          \
    t3_ = fmaf(dppf<0x123>(shv), Wror[3],  t3_);          \
    t0_ = fmaf(dppf<0x124>(shv), Wror[4],  t0_);          \
    t1_ = fmaf(dppf<0x125>(shv), Wror[5],  t1_);          \
    t2_ = fmaf(dppf<0x126>(shv), Wror[6],  t2_);          \
    t3_ = fmaf(dppf<0x127>(shv), Wror[7],  t3_);          \
    t0_ = fmaf(dppf<0x128>(shv), Wror[8],  t0_);          \
    t1_ = fmaf(dppf<0x129>(shv), Wror[9],  t1_);          \
    t2_ = fmaf(dppf<0x12A>(shv), Wror[10], t2_);          \
    t3_ = fmaf(dppf<0x12B>(shv), Wror[11], t3_);          \
    t0_ = fmaf(dppf<0x12C>(shv), Wror[12], t0_);          \
    t1_ = fmaf(dppf<0x12D>(shv), Wror[13], t1_);          \
    t2_ = fmaf(dppf<0x12E>(shv), Wror[14], t2_);          \
    t3_ = fmaf(dppf<0x12F>(shv), Wror[15], t3_);          \
    tot = (t0_ + t1_) + (t2_ + t3_); }

// One direction's scan. fwd: v_t = mask ? diag(p_t)·W^T·v_{t-1} : v_{t-1},
// t=1..255 (init v_0 = exp(logit_0)). bwd: u_{t-1} = mask_t ? W·(p_t∘u_t) : u_t,
// t=511..256 (init u_511 = 1). All f32, renorm every 8 steps.
template<bool BWD>
__device__ __forceinline__ void scan(const float* __restrict__ ep,
                                     const int* __restrict__ ys,
                                     const float (&Wror)[16],
                                     int j, int jm,
                                     float& ownO, float& MO, float& eaccO) {
  float own, M, eacc;
  float ebuf[8]; int ybuf[8];
  if (!BWD) {
    const float a0 = ep[0];
    const int y0 = ys[0];
    eacc = (y0 == jm) ? a0 : 0.f;
    const float A = (j < 15) ? a0 * L2E : -1.0e30f;
    const float M0 = bflymax16(A);
    own = exp2f(A - M0);
    M = M0;
    #pragma unroll
    for (int i = 0; i < 8; ++i) { ebuf[i] = ep[(1 + i) * 15]; ybuf[i] = ys[1 + i]; }
  } else {
    eacc = 0.f;
    own = (j < 15) ? 1.f : 0.f;
    M = 0.f;
    #pragma unroll
    for (int i = 0; i < 8; ++i) { ebuf[i] = ep[(511 - i) * 15]; ybuf[i] = ys[511 - i]; }
  }

  if (!BWD) {
    for (int sb = 0; sb < 31; ++sb) {          // t = 1..248
      #pragma unroll
      for (int k = 0; k < 8; ++k) {
        const int t = 1 + sb * 8 + k;
        const float emit = ebuf[k]; const int yv = ybuf[k];
        const int tn = (t + 8 > 255) ? 255 : t + 8;
        ebuf[k] = ep[tn * 15]; ybuf[k] = ys[tn];
        const float p = exp2f(emit * L2E);
        float tot; DOT(own, tot);
        const float cand = tot * p;
        own = (yv != 15) ? cand : own;
        eacc += (yv == jm) ? emit : 0.f;
        if (k == 7) {
          const float m = bflymax16(own);
          own *= __builtin_amdgcn_rcpf(m);
          M += log2f(m);
        }
      }
    }
    #pragma unroll
    for (int k = 0; k < 7; ++k) {              // t = 249..255
      const float emit = ebuf[k]; const int yv = ybuf[k];
      const float p = exp2f(emit * L2E);
      float tot; DOT(own, tot);
      const float cand = tot * p;
      own = (yv != 15) ? cand : own;
      eacc += (yv == jm) ? emit : 0.f;
    }
  } else {
    for (int sb = 0; sb < 32; ++sb) {          // t = 511..256
      #pragma unroll
      for (int k = 0; k < 8; ++k) {
        const int t = 511 - (sb * 8 + k);
        const float emit = ebuf[k]; const int yv = ybuf[k];
        const int tn = (t - 8 < 256) ? 256 : t - 8;
        ebuf[k] = ep[tn * 15]; ybuf[k] = ys[tn];
        const float p = exp2f(emit * L2E);
        const float share = own * p;
        float tot; DOT(share, tot);
        own = (yv != 15) ? tot : own;
        eacc += (yv == jm) ? emit : 0.f;
        if (k == 7) {
          const float m = bflymax16(own);
          own *= __builtin_amdgcn_rcpf(m);
          M += log2f(m);
        }
      }
    }
  }
  ownO = own; MO = M; eaccO = eacc;
}

__global__ __launch_bounds__(256, 2)
void crf_rot(const float* __restrict__ logits, const int* __restrict__ yg,
             const float* __restrict__ trans, float* __restrict__ out) {
  __shared__ float Tl[240];
  __shared__ int   yl[8 * 512];
  __shared__ float comb[8][2][16];
  __shared__ float pathE[8][2];
  __shared__ float transS[8];
  __shared__ float blks[8];

  const int tid = threadIdx.x;
  if (tid < 225) Tl[tid] = trans[tid];
  {
    const int4* src = (const int4*)(yg + (size_t)blockIdx.x * 4096);
    int4* dst = (int4*)yl;
    #pragma unroll
    for (int k = 0; k < 4; ++k) dst[tid + k * 256] = src[tid + k * 256];
  }
  __syncthreads();

  // ---- transition part of path score (LDS-only; 32 threads/seq, t=1..511) ----
  {
    const int q = tid >> 5, l32 = tid & 31;
    const int* ys = yl + q * 512;
    float acc = 0.f;
    #pragma unroll
    for (int m = 0; m < 16; ++m) {
      const int t = 1 + l32 + 32 * m;
      if (t < 512) {
        const int yc = ys[t], yp = ys[t - 1];
        if (yc < 15 && yp < 15) acc += Tl[yp * 15 + yc];
      }
    }
    #pragma unroll
    for (int k = 1; k < 32; k <<= 1) acc += __shfl_xor(acc, k, 32);
    if (l32 == 0) transS[q] = acc;
  }

  // ---- chain setup: 16 lanes/chain, 4 chains/wave; whole wave is fwd or bwd ----
  const int wave = tid >> 6, lane = tid & 63;
  const int j = lane & 15;
  const int sLoc = (wave >> 1) * 4 + (lane >> 4);   // 0..7
  const bool isFwd = (wave & 1) == 0;
  const int seq = blockIdx.x * 8 + sLoc;
  const int jj = (j < 15) ? j : 14;
  const int jm = (j < 15) ? j : 255;
  const float* ep = logits + (size_t)seq * 7680 + jj;
  const int* ys = yl + sLoc * 512;

  // Wror[r][j] = exp(T[src][j]) (fwd) / exp(T[j][src]) (bwd), src from the
  // actual DPP rotation applied to the lane index (direction-proof).
  float Wror[16];
  Wror[0] = (j < 15) ? exp2f(Tl[j * 16] * L2E) : 0.f;
#define SETW(R) { const int s_ = dppi<0x120 + (R)>(j);                  \
    const bool v_ = (j < 15) && (s_ < 15);                              \
    const int ix_ = isFwd ? s_ * 15 + j : j * 15 + s_;                  \
    Wror[R] = v_ ? exp2f(Tl[ix_] * L2E) : 0.f; }
  SETW(1)  SETW(2)  SETW(3)  SETW(4)  SETW(5)
  SETW(6)  SETW(7)  SETW(8)  SETW(9)  SETW(10)
  SETW(11) SETW(12) SETW(13) SETW(14) SETW(15)
#undef SETW

  float own, M, eacc;
  if (isFwd) scan<false>(ep, ys, Wror, j, jm, own, M, eacc);
  else       scan<true >(ep, ys, Wror, j, jm, own, M, eacc);

  const int dir = isFwd ? 0 : 1;
  if (j < 15) comb[sLoc][dir][j] = M + log2f(own);
  #pragma unroll
  for (int k = 1; k < 16; k <<= 1) eacc += __shfl_xor(eacc, k, 16);
  if (j == 0) pathE[sLoc][dir] = eacc;

  __syncthreads();

  // ---- per-sequence combine: logZ = lse_i(log v_255[i] + log u_255[i]) ----
  if (tid < 8) {
    float mx = -3.0e38f; float s[15];
    #pragma unroll
    for (int i = 0; i < 15; ++i) {
      s[i] = comb[tid][0][i] + comb[tid][1][i];
      mx = fmaxf(mx, s[i]);
    }
    float sum = 0.f;
    #pragma unroll
    for (int i = 0; i < 15; ++i) sum += exp2f(s[i] - mx);
    const float logZ = (mx + log2f(sum)) * LN2f;
    const float path = pathE[tid][0] + pathE[tid][1] + transS[tid];
    float nll = logZ - path;
    nll = fminf(fmaxf(nll, 0.f), 1000000.f);
    blks[tid] = nll;
  }
  __syncthreads();
  if (tid == 0) {
    float tot = (blks[0] + blks[1]) + (blks[2] + blks[3]) +
                (blks[4] + blks[5]) + (blks[6] + blks[7]);
    atomicAdd(out, tot * (1.0f / 4096.0f));
  }
}

extern "C" void kernel_launch(void* const* d_in, const int* in_sizes, int n_in,
                              void* d_out, int out_size, void* d_ws, size_t ws_size,
                              hipStream_t stream) {
  const float* logits = (const float*)d_in[0];   // (4096, 512, 15) f32
  const int*   y      = (const int*)d_in[1];     // (4096, 512) i32
  const float* trans  = (const float*)d_in[2];   // (15, 15) f32
  float* out = (float*)d_out;

  hipMemsetAsync(out, 0, sizeof(float), stream);

  const int B = in_sizes[1] / 512;               // 4096
  crf_rot<<<dim3(B / 8), dim3(256), 0, stream>>>(logits, y, trans, out);
}

// Round 5
// 63.549 us; speedup vs baseline: 1.2451x; 1.0769x over previous
//
#include <hip/hip_runtime.h>

#define L2E  1.4426950408889634f
#define LN2f 0.6931471805599453f

template<int CTRL>
__device__ __forceinline__ float dppf(float x) {
  int r = __builtin_amdgcn_update_dpp(0, __builtin_bit_cast(int, x), CTRL, 0xF, 0xF, true);
  return __builtin_bit_cast(float, r);
}
template<int CTRL>
__device__ __forceinline__ int dppi(int x) {
  return __builtin_amdgcn_update_dpp(0, x, CTRL, 0xF, 0xF, true);
}

// max over the 16-lane group via DPP butterfly; ctrl set verified (R2/R4, absmax 0)
__device__ __forceinline__ float bflymax16(float x) {
  x = fmaxf(x, dppf<0xB1>(x));    // lane^1
  x = fmaxf(x, dppf<0x4E>(x));    // lane^2
  x = fmaxf(x, dppf<0x141>(x));   // lane^7
  x = fmaxf(x, dppf<0x140>(x));   // lane^15
  return x;
}

// Fused rotate-and-dot (verified in R4): tot_j = sum_r rot_r(shv)_j * Wror[r]_j
#define DOT(shv, tot) {                                   \
    float t0_ = (shv) * Wror[0], t1_ = 0.f, t2_ = 0.f, t3_ = 0.f; \
    t1_ = fmaf(dppf<0x121>(shv), Wror[1],  t1_);          \
    t2_ = fmaf(dppf<0x122>(shv), Wror[2],  t2_);          \
    t3_ = fmaf(dppf<0x123>(shv), Wror[3],  t3_);          \
    t0_ = fmaf(dppf<0x124>(shv), Wror[4],  t0_);          \
    t1_ = fmaf(dppf<0x125>(shv), Wror[5],  t1_);          \
    t2_ = fmaf(dppf<0x126>(shv), Wror[6],  t2_);          \
    t3_ = fmaf(dppf<0x127>(shv), Wror[7],  t3_);          \
    t0_ = fmaf(dppf<0x128>(shv), Wror[8],  t0_);          \
    t1_ = fmaf(dppf<0x129>(shv), Wror[9],  t1_);          \
    t2_ = fmaf(dppf<0x12A>(shv), Wror[10], t2_);          \
    t3_ = fmaf(dppf<0x12B>(shv), Wror[11], t3_);          \
    t0_ = fmaf(dppf<0x12C>(shv), Wror[12], t0_);          \
    t1_ = fmaf(dppf<0x12D>(shv), Wror[13], t1_);          \
    t2_ = fmaf(dppf<0x12E>(shv), Wror[14], t2_);          \
    t3_ = fmaf(dppf<0x12F>(shv), Wror[15], t3_);          \
    tot = (t0_ + t1_) + (t2_ + t3_); }

// One direction's scan (math identical to R4, absmax 0). Linear-pointer
// prefetch, no clamps: fwd over-reads to t<=263 (<512), bwd down to t>=248
// (>=0) -- in-bounds, values unused. LDS y array padded (stride 520).
template<bool BWD>
__device__ __forceinline__ void scan(const float* __restrict__ ep,
                                     const int* __restrict__ ys,
                                     const float (&Wror)[16],
                                     int j, int jm,
                                     float& ownO, float& MO, float& eaccO) {
  float own, M, eacc;
  float ebuf[8]; int ybuf[8];
  const float* pe;
  const int* py;
  if (!BWD) {
    const float a0 = ep[0];
    const int y0 = ys[0];
    eacc = (y0 == jm) ? a0 : 0.f;
    const float A = (j < 15) ? a0 * L2E : -1.0e30f;
    const float M0 = bflymax16(A);
    own = exp2f(A - M0);
    M = M0;
    #pragma unroll
    for (int i = 0; i < 8; ++i) { ebuf[i] = ep[(1 + i) * 15]; ybuf[i] = ys[1 + i]; }
    pe = ep + 9 * 15;
    py = ys + 9;
  } else {
    eacc = 0.f;
    own = (j < 15) ? 1.f : 0.f;
    M = 0.f;
    #pragma unroll
    for (int i = 0; i < 8; ++i) { ebuf[i] = ep[(511 - i) * 15]; ybuf[i] = ys[511 - i]; }
    pe = ep + (511 - 8) * 15;
    py = ys + (511 - 8);
  }

  if (!BWD) {
    for (int sb = 0; sb < 31; ++sb) {          // t = 1..248
      #pragma unroll
      for (int k = 0; k < 8; ++k) {
        const float emit = ebuf[k]; const int yv = ybuf[k];
        ebuf[k] = *pe; pe += 15;
        ybuf[k] = *py; py += 1;
        const float p = exp2f(emit * L2E);
        float tot; DOT(own, tot);
        const float cand = tot * p;
        own = (yv != 15) ? cand : own;
        eacc += (yv == jm) ? emit : 0.f;
        if (k == 7) {
          const float m = bflymax16(own);
          own *= __builtin_amdgcn_rcpf(m);
          M += log2f(m);
        }
      }
    }
    #pragma unroll
    for (int k = 0; k < 7; ++k) {              // t = 249..255
      const float emit = ebuf[k]; const int yv = ybuf[k];
      ebuf[k] = *pe; pe += 15;                 // harmless over-prefetch (t<=263)
      const float p = exp2f(emit * L2E);
      float tot; DOT(own, tot);
      const float cand = tot * p;
      own = (yv != 15) ? cand : own;
      eacc += (yv == jm) ? emit : 0.f;
    }
  } else {
    for (int sb = 0; sb < 32; ++sb) {          // t = 511..256
      #pragma unroll
      for (int k = 0; k < 8; ++k) {
        const float emit = ebuf[k]; const int yv = ybuf[k];
        ebuf[k] = *pe; pe -= 15;               // over-prefetch down to t=248
        ybuf[k] = *py; py -= 1;
        const float p = exp2f(emit * L2E);
        const float share = own * p;
        float tot; DOT(share, tot);
        own = (yv != 15) ? tot : own;
        eacc += (yv == jm) ? emit : 0.f;
        if (k == 7) {
          const float m = bflymax16(own);
          own *= __builtin_amdgcn_rcpf(m);
          M += log2f(m);
        }
      }
    }
  }
  ownO = own; MO = M; eaccO = eacc;
}

__global__ __launch_bounds__(256, 2)
void crf_rot(const float* __restrict__ logits, const int* __restrict__ yg,
             const float* __restrict__ trans, float* __restrict__ out) {
  __shared__ float Tl[240];
  __shared__ int   yl[8 * 520];    // stride 520 ints: bank shift 8/seq -> no 4-way alias
  __shared__ float comb[8][2][16];
  __shared__ float pathE[8][2];
  __shared__ float transS[8];
  __shared__ float blks[8];

  const int tid = threadIdx.x;
  if (tid < 225) Tl[tid] = trans[tid];
  {
    // stage 8 seqs x 512 ints with padded per-seq stride (130 int4 = 520 ints)
    const int4* src = (const int4*)(yg + (size_t)blockIdx.x * 4096);
    int4* dst = (int4*)yl;
    #pragma unroll
    for (int k = 0; k < 4; ++k) {
      const int g = tid + k * 256;             // 0..1023
      const int sq = g >> 7, pos = g & 127;
      dst[sq * 130 + pos] = src[g];
    }
  }
  __syncthreads();

  // ---- transition part of path score (LDS-only; 32 threads/seq, t=1..511) ----
  {
    const int q = tid >> 5, l32 = tid & 31;
    const int* ys = yl + q * 520;
    float acc = 0.f;
    #pragma unroll
    for (int m = 0; m < 16; ++m) {
      const int t = 1 + l32 + 32 * m;
      if (t < 512) {
        const int yc = ys[t], yp = ys[t - 1];
        if (yc < 15 && yp < 15) acc += Tl[yp * 15 + yc];
      }
    }
    #pragma unroll
    for (int k = 1; k < 32; k <<= 1) acc += __shfl_xor(acc, k, 32);
    if (l32 == 0) transS[q] = acc;
  }

  // ---- chain setup: 16 lanes/chain, 4 chains/wave; whole wave is fwd or bwd ----
  const int wave = tid >> 6, lane = tid & 63;
  const int j = lane & 15;
  const int sLoc = (wave >> 1) * 4 + (lane >> 4);   // 0..7
  const bool isFwd = (wave & 1) == 0;
  const int seq = blockIdx.x * 8 + sLoc;
  const int jj = (j < 15) ? j : 14;
  const int jm = (j < 15) ? j : 255;
  const float* ep = logits + (size_t)seq * 7680 + jj;
  const int* ys = yl + sLoc * 520;

  // Wror[r][j] = exp(T[src][j]) (fwd) / exp(T[j][src]) (bwd); src derived by
  // applying the SAME DPP op to the lane index (direction-proof; R4-verified).
  float Wror[16];
  Wror[0] = (j < 15) ? exp2f(Tl[j * 16] * L2E) : 0.f;
#define SETW(R) { const int s_ = dppi<0x120 + (R)>(j);                  \
    const bool v_ = (j < 15) && (s_ < 15);                              \
    const int ix_ = isFwd ? s_ * 15 + j : j * 15 + s_;                  \
    Wror[R] = v_ ? exp2f(Tl[ix_] * L2E) : 0.f; }
  SETW(1)  SETW(2)  SETW(3)  SETW(4)  SETW(5)
  SETW(6)  SETW(7)  SETW(8)  SETW(9)  SETW(10)
  SETW(11) SETW(12) SETW(13) SETW(14) SETW(15)
#undef SETW
  // Pin Wror in VGPRs: opaque asm stops the compiler from rematerializing
  // exp2f(Tl[...]) inside the scan loop (R4: VGPR_Count=40 => it did).
  #pragma unroll
  for (int r = 0; r < 16; ++r) asm volatile("" : "+v"(Wror[r]));

  float own, M, eacc;
  if (isFwd) scan<false>(ep, ys, Wror, j, jm, own, M, eacc);
  else       scan<true >(ep, ys, Wror, j, jm, own, M, eacc);

  const int dir = isFwd ? 0 : 1;
  if (j < 15) comb[sLoc][dir][j] = M + log2f(own);
  #pragma unroll
  for (int k = 1; k < 16; k <<= 1) eacc += __shfl_xor(eacc, k, 16);
  if (j == 0) pathE[sLoc][dir] = eacc;

  __syncthreads();

  // ---- per-sequence combine: logZ = lse_i(log v_255[i] + log u_255[i]) ----
  if (tid < 8) {
    float mx = -3.0e38f; float s[15];
    #pragma unroll
    for (int i = 0; i < 15; ++i) {
      s[i] = comb[tid][0][i] + comb[tid][1][i];
      mx = fmaxf(mx, s[i]);
    }
    float sum = 0.f;
    #pragma unroll
    for (int i = 0; i < 15; ++i) sum += exp2f(s[i] - mx);
    const float logZ = (mx + log2f(sum)) * LN2f;
    const float path = pathE[tid][0] + pathE[tid][1] + transS[tid];
    float nll = logZ - path;
    nll = fminf(fmaxf(nll, 0.f), 1000000.f);
    blks[tid] = nll;
  }
  __syncthreads();
  if (tid == 0) {
    float tot = (blks[0] + blks[1]) + (blks[2] + blks[3]) +
                (blks[4] + blks[5]) + (blks[6] + blks[7]);
    atomicAdd(out, tot * (1.0f / 4096.0f));
  }
}

extern "C" void kernel_launch(void* const* d_in, const int* in_sizes, int n_in,
                              void* d_out, int out_size, void* d_ws, size_t ws_size,
                              hipStream_t stream) {
  const float* logits = (const float*)d_in[0];   // (4096, 512, 15) f32
  const int*   y      = (const int*)d_in[1];     // (4096, 512) i32
  const float* trans  = (const float*)d_in[2];   // (15, 15) f32
  float* out = (float*)d_out;

  hipMemsetAsync(out, 0, sizeof(float), stream);

  const int B = in_sizes[1] / 512;               // 4096
  crf_rot<<<dim3(B / 8), dim3(256), 0, stream>>>(logits, y, trans, out);
}